// Round 9
// baseline (4544.975 us; speedup 1.0000x reference)
//
#include <hip/hip_runtime.h>
#include <math.h>

// Sinkhorn divergence (geomloss 'sinkhorn', debias=True) with quaternion
// geodesic cost, B=8, P=2048, D=4.
//
// R20 = R17 (fence REVERTED -- R19's __threadfence_system made init 81->305us;
// per-wave system fences serialize on L2 writeback+invalidate) with the
// steady-pass decode loop widened to uint4 loads.
// Toll verdict after R14-R19: the ~105us first-reader toll on freshly
// written mats is demand-driven and cannot be pre-paid cheaper than the
// first decode pass already pays it (warm reader = 127us, NT stores =
// neutral, time-decay ~0.2 TB/s, fence = catastrophic). ACCEPTED as fixed.
// Remaining lever: steady passes (12 x 24.6us = 295us) run at 5.45 of the
// 6.29 TB/s ceiling with only one dword load per lane per step (256B/wave
// in flight x8). uint4 widening: 1KB/wave/instruction, 8KB in flight per
// t-step, LDS Hs reads as float4 (pairing layout lines up: byte q of dword
// d pairs Hs4[d/4 + 128q]). Expect ~5.9-6.1 TB/s -> ~22.5us/pass.
//
// Carried: fused init (plain u8 stores, softmin from unrounded costs, diag
// exact via u>=1e-6 clip); mats force diag byte 255 (cost=pi); steady decode
// adds cancellation-free residual exp2(h_i - mh + ldfac) (R13 scheme);
// tiered n_mats {4..0}; packing: dword at (row*512 + d) packs cols
// {d, d+512, d+1024, d+1536}.

#define BATCH 8
#define NP    2048
#define NPOT  (BATCH * NP)                    // 16384 floats per potential
#define MAT_ELEMS  ((size_t)BATCH * NP * NP)  // 33,554,432 u8 per matrix
#define MAT_DWORDS (MAT_ELEMS / 4)            // 8,388,608 dwords
#define MAT_BYTES  (MAT_ELEMS)                // 33,554,432 bytes (32 MiB)

__device__ __forceinline__ float bcastf(float v) {
  return __int_as_float(__builtin_amdgcn_readfirstlane(__float_as_int(v)));
}

// unrounded cost in u8 code units: 2*acos(|<q,p>|) * 255/pi
__device__ __forceinline__ float qcostf(
    float qx, float qy, float qz, float qw, float4 p,
    float P0, float P1, float P2, float P3)
{
  const float dt = fmaf(qx, p.x, fmaf(qy, p.y, fmaf(qz, p.z, qw * p.w)));
  const float u  = fmaxf(1.0f - fabsf(dt), 1e-6f);
  const float sq = __builtin_amdgcn_sqrtf(u);
  const float g  = fmaf(fmaf(fmaf(P3, u, P2), u, P1), u, P0);
  return sq * g;   // in [0, 255.01]
}

// ---------------------------------------------------------------------------
// Fused init pass (R17-proven): computes float costs (code units), packs u8
// codes, stores them for s < n_mats, computes the init softmin (mh=0,
// Hs=log2(w)) from the UNROUNDED costs. Replace-mode output.
// s=0: rows=x cols=y (Cxy); s=1: rows=y cols=x (Cyx);
// s=2: rows=x cols=x (Cxx); s=3: rows=y cols=y (Cyy).
// ---------------------------------------------------------------------------
__global__ __launch_bounds__(512, 8) void sink_init_fused(
    const float* __restrict__ x, const float* __restrict__ y,
    const float* __restrict__ wx, const float* __restrict__ wy,
    unsigned int* __restrict__ mats, int n_mats,
    float* __restrict__ pot_new,
    float eps, float kdec,
    float P0, float P1, float P2, float P3,
    float B0, float B1, float B2, float B3)
{
  const int bid  = blockIdx.x;         // grid 1024: s(4) x b(8) x rg(32)
  const int s    = bid >> 8;
  const int b    = (bid >> 5) & 7;
  const int rg   = bid & 31;
  const int tid  = threadIdx.x;
  const int lane = tid & 63;

  __shared__ float4 Pts[NP];   // 32 KB
  __shared__ float  Hs[NP];    //  8 KB

  const float4* colp; const float* colw; const float4* rowp;
  if (s == 0)      { colp=(const float4*)y; colw=wy; rowp=(const float4*)x; }
  else if (s == 1) { colp=(const float4*)x; colw=wx; rowp=(const float4*)y; }
  else if (s == 2) { colp=(const float4*)x; colw=wx; rowp=(const float4*)x; }
  else             { colp=(const float4*)y; colw=wy; rowp=(const float4*)y; }
  colp += b * NP; colw += b * NP;

  #pragma unroll
  for (int t = 0; t < 4; ++t) {
    const int idx = tid + t * 512;
    Pts[idx] = colp[idx];
    Hs[idx]  = __builtin_amdgcn_logf(colw[idx]);   // log2(w); NO pot read
  }
  __syncthreads();

  const int wvu = __builtin_amdgcn_readfirstlane(tid >> 6);
  const int i0  = rg * 64 + wvu * 8;
  const int oidx = s * NPOT + b * NP + i0;
  const bool dg    = (s >= 2);
  const bool store = (s < n_mats);

  float qx[8], qy[8], qz[8], qw[8];
  #pragma unroll
  for (int r = 0; r < 8; ++r) {
    const float4 t4 = rowp[b * NP + i0 + r];
    qx[r] = bcastf(t4.x); qy[r] = bcastf(t4.y);
    qz[r] = bcastf(t4.z); qw[r] = bcastf(t4.w);
  }

  unsigned int* obase = mats + (size_t)s * MAT_DWORDS
                      + (((size_t)(b * NP + i0)) << 9);

  float mh[8];
  float ss[8];
  #pragma unroll
  for (int r = 0; r < 8; ++r) { mh[r] = 0.0f; ss[r] = 0.0f; }

  for (int t = 0; t < 8; ++t) {
    const int j = t * 64 + lane;
    const float4 p0 = Pts[j];
    const float4 p1 = Pts[j + 512];
    const float4 p2 = Pts[j + 1024];
    const float4 p3 = Pts[j + 1536];
    const float h0 = Hs[j];
    const float h1 = Hs[j + 512];
    const float h2 = Hs[j + 1024];
    const float h3 = Hs[j + 1536];
    #pragma unroll
    for (int r = 0; r < 8; ++r) {
      const float c0 = qcostf(qx[r], qy[r], qz[r], qw[r], p0, P0, P1, P2, P3);
      const float c1 = qcostf(qx[r], qy[r], qz[r], qw[r], p1, P0, P1, P2, P3);
      const float c2 = qcostf(qx[r], qy[r], qz[r], qw[r], p2, P0, P1, P2, P3);
      const float c3 = qcostf(qx[r], qy[r], qz[r], qw[r], p3, P0, P1, P2, P3);
      if (store) {
        const unsigned int a0 = (unsigned int)(c0 + 0.5f);
        const unsigned int a1 = (unsigned int)(c1 + 0.5f);
        const unsigned int a2 = (unsigned int)(c2 + 0.5f);
        const unsigned int a3 = (unsigned int)(c3 + 0.5f);
        unsigned int pack = a0 | (a1 << 8) | (a2 << 16) | (a3 << 24);
        if (dg) {
          const int c = i0 + r;                  // diag column for this row
          if (j == (c & 511))
            pack |= 0xFFu << ((c >> 9) << 3);    // diag code 0 -> OR sets 255
        }
        obase[(r << 9) + j] = pack;
      }
      // softmin from the unrounded costs (diag exact via the u>=1e-6 clip)
      ss[r] += __builtin_amdgcn_exp2f(fmaf(c0, -kdec, h0))
             + __builtin_amdgcn_exp2f(fmaf(c1, -kdec, h1))
             + __builtin_amdgcn_exp2f(fmaf(c2, -kdec, h2))
             + __builtin_amdgcn_exp2f(fmaf(c3, -kdec, h3));
    }
  }
  #pragma unroll
  for (int r = 0; r < 8; ++r) {
    float sv = ss[r];
    #pragma unroll
    for (int off = 32; off >= 1; off >>= 1)
      sv += __shfl_xor(sv, off, 64);
    ss[r] = sv;
  }

  // safety net: full-precision recompute from Pts (independent of mats)
  #pragma unroll
  for (int r = 0; r < 8; ++r) {
    const bool good = (ss[r] >= 8.6736174e-19f) && (ss[r] <= 1.1529215e18f);
    if (!good) {
      float mv = -3.0e38f;
      for (int t = 0; t < 32; ++t) {
        const int j = t * 64 + lane;
        const float4 p = Pts[j];
        const float dt = fmaf(qx[r], p.x,
                          fmaf(qy[r], p.y, fmaf(qz[r], p.z, qw[r] * p.w)));
        const float u  = fmaxf(1.0f - fabsf(dt), 1e-6f);
        const float sq = __builtin_amdgcn_sqrtf(u);
        const float pl = fmaf(fmaf(fmaf(B3, u, B2), u, B1), u, B0);
        mv = fmaxf(mv, fmaf(sq, -pl, Hs[j]));
      }
      #pragma unroll
      for (int off = 32; off >= 1; off >>= 1)
        mv = fmaxf(mv, __shfl_xor(mv, off, 64));
      mh[r] = mv;
      float sv = 0.0f;
      for (int t = 0; t < 32; ++t) {
        const int j = t * 64 + lane;
        const float4 p = Pts[j];
        const float dt = fmaf(qx[r], p.x,
                          fmaf(qy[r], p.y, fmaf(qz[r], p.z, qw[r] * p.w)));
        const float u  = fmaxf(1.0f - fabsf(dt), 1e-6f);
        const float sq = __builtin_amdgcn_sqrtf(u);
        const float pl = fmaf(fmaf(fmaf(B3, u, B2), u, B1), u, B0);
        sv += __builtin_amdgcn_exp2f(fmaf(sq, -pl, Hs[j]) - mv);
      }
      #pragma unroll
      for (int off = 32; off >= 1; off >>= 1)
        sv += __shfl_xor(sv, off, 64);
      ss[r] = sv;
    }
  }

  if (lane == 0) {
    #pragma unroll
    for (int r = 0; r < 8; ++r)
      pot_new[oidx + r] = -eps * 0.69314718055994531f
                        * (mh[r] + __builtin_amdgcn_logf(ss[r]));
  }
}

// ---------------------------------------------------------------------------
// Steady pass: s < n_mats -> u8 decode path (uint4-widened); else R10
// recompute path.
// ---------------------------------------------------------------------------
__global__ __launch_bounds__(512, 8) void sink_pass_r20(
    const float* __restrict__ x, const float* __restrict__ y,
    const float* __restrict__ wx, const float* __restrict__ wy,
    const unsigned int* __restrict__ mats, int n_mats,
    const float* __restrict__ pot_old, float* __restrict__ pot_new,
    float eps, float c1 /* log2e/eps */,
    float seed_s /* -log2e/eps */,
    float kdec /* (pi/255)*log2e/eps */,
    float ldfac /* log2(exp(-C_diag/eps) - exp(-pi/eps)) */,
    float B0, float B1, float B2, float B3 /* acos(u)-poly * 2*log2e/eps */,
    int use_avg)
{
  const int bid  = blockIdx.x;         // grid 1024: s(4) x b(8) x rg(32)
  const int s    = bid >> 8;
  const int b    = (bid >> 5) & 7;
  const int rg   = bid & 31;
  const int tid  = threadIdx.x;
  const int lane = tid & 63;

  __shared__ float4 Pts[NP];           // 32 KB (recompute path only)
  __shared__ float4 HsV[NP / 4];       //  8 KB, float4-aligned for b128 reads
  float* Hs = (float*)HsV;

  const float4* colp; const float* colw; const float* colpot; const float4* rowp;
  if (s == 0)      { colp=(const float4*)y; colw=wy; colpot=pot_old+1*NPOT; rowp=(const float4*)x; }
  else if (s == 1) { colp=(const float4*)x; colw=wx; colpot=pot_old+0*NPOT; rowp=(const float4*)y; }
  else if (s == 2) { colp=(const float4*)x; colw=wx; colpot=pot_old+2*NPOT; rowp=(const float4*)x; }
  else             { colp=(const float4*)y; colw=wy; colpot=pot_old+3*NPOT; rowp=(const float4*)y; }
  colp += b * NP; colw += b * NP; colpot += b * NP;

  const bool use_mat = (s < n_mats);
  const bool do_diag = use_mat && (s >= 2);

  if (use_mat) {
    #pragma unroll
    for (int t = 0; t < 4; ++t) {
      const int idx = tid + t * 512;
      Hs[idx] = fmaf(colpot[idx], c1, __builtin_amdgcn_logf(colw[idx]));
    }
  } else {
    #pragma unroll
    for (int t = 0; t < 4; ++t) {
      const int idx = tid + t * 512;
      Pts[idx] = colp[idx];
      Hs[idx] = fmaf(colpot[idx], c1, __builtin_amdgcn_logf(colw[idx]));
    }
  }
  __syncthreads();

  const int wvu = __builtin_amdgcn_readfirstlane(tid >> 6);
  const int i0  = rg * 64 + wvu * 8;
  const int oidx = s * NPOT + b * NP + i0;
  float mh[8];
  #pragma unroll
  for (int r = 0; r < 8; ++r)
    mh[r] = bcastf(pot_old[oidx + r] * seed_s);

  float ss[8] = {0.f, 0.f, 0.f, 0.f, 0.f, 0.f, 0.f, 0.f};

  if (use_mat) {
    // ---------------- u8 decode path, uint4-widened ----------------
    // uint4 at index k covers dwords 4k..4k+3; dword d holds cols
    // {d, d+512, d+1024, d+1536} -> byte q of the 4 dwords pairs with
    // HsV[k + 128*q] (float4 of cols 4k..4k+3 shifted by 512q).
    const uint4* mrow4 = (const uint4*)(mats + (size_t)s * MAT_DWORDS
                             + (((size_t)(b * NP + i0)) << 9));
    for (int t2 = 0; t2 < 2; ++t2) {
      const int k = t2 * 64 + lane;        // uint4 index within row
      const float4 h0 = HsV[k];
      const float4 h1 = HsV[k + 128];
      const float4 h2 = HsV[k + 256];
      const float4 h3 = HsV[k + 384];
      #pragma unroll
      for (int r = 0; r < 8; ++r) {
        const uint4 U = mrow4[(r << 7) + k];   // 128 uint4 per row
        const float m = mh[r];
        ss[r] += __builtin_amdgcn_exp2f(fmaf((float)(U.x & 0xFFu),         -kdec, h0.x - m))
               + __builtin_amdgcn_exp2f(fmaf((float)(U.y & 0xFFu),         -kdec, h0.y - m))
               + __builtin_amdgcn_exp2f(fmaf((float)(U.z & 0xFFu),         -kdec, h0.z - m))
               + __builtin_amdgcn_exp2f(fmaf((float)(U.w & 0xFFu),         -kdec, h0.w - m));
        ss[r] += __builtin_amdgcn_exp2f(fmaf((float)((U.x >> 8) & 0xFFu),  -kdec, h1.x - m))
               + __builtin_amdgcn_exp2f(fmaf((float)((U.y >> 8) & 0xFFu),  -kdec, h1.y - m))
               + __builtin_amdgcn_exp2f(fmaf((float)((U.z >> 8) & 0xFFu),  -kdec, h1.z - m))
               + __builtin_amdgcn_exp2f(fmaf((float)((U.w >> 8) & 0xFFu),  -kdec, h1.w - m));
        ss[r] += __builtin_amdgcn_exp2f(fmaf((float)((U.x >> 16) & 0xFFu), -kdec, h2.x - m))
               + __builtin_amdgcn_exp2f(fmaf((float)((U.y >> 16) & 0xFFu), -kdec, h2.y - m))
               + __builtin_amdgcn_exp2f(fmaf((float)((U.z >> 16) & 0xFFu), -kdec, h2.z - m))
               + __builtin_amdgcn_exp2f(fmaf((float)((U.w >> 16) & 0xFFu), -kdec, h2.w - m));
        ss[r] += __builtin_amdgcn_exp2f(fmaf((float)(U.x >> 24),           -kdec, h3.x - m))
               + __builtin_amdgcn_exp2f(fmaf((float)(U.y >> 24),           -kdec, h3.y - m))
               + __builtin_amdgcn_exp2f(fmaf((float)(U.z >> 24),           -kdec, h3.z - m))
               + __builtin_amdgcn_exp2f(fmaf((float)(U.w >> 24),           -kdec, h3.w - m));
      }
    }
    #pragma unroll
    for (int r = 0; r < 8; ++r) {
      float sv = ss[r];
      #pragma unroll
      for (int off = 32; off >= 1; off >>= 1)
        sv += __shfl_xor(sv, off, 64);
      if (do_diag)
        sv += __builtin_amdgcn_exp2f(Hs[i0 + r] - mh[r] + ldfac);
      ss[r] = sv;
    }
    // safety net: two-phase decode re-sweep for out-of-band rows (cold)
    const unsigned int* mrow = mats + (size_t)s * MAT_DWORDS
                             + (((size_t)(b * NP + i0)) << 9);
    #pragma unroll
    for (int r = 0; r < 8; ++r) {
      const bool good = (ss[r] >= 8.6736174e-19f) && (ss[r] <= 1.1529215e18f);
      if (!good) {
        float mv = -3.0e38f;
        for (int t = 0; t < 8; ++t) {
          const int j = t * 64 + lane;
          const unsigned int U = mrow[(r << 9) + j];
          mv = fmaxf(mv, fmaf((float)(U & 0xFFu),         -kdec, Hs[j]));
          mv = fmaxf(mv, fmaf((float)((U >> 8) & 0xFFu),  -kdec, Hs[j + 512]));
          mv = fmaxf(mv, fmaf((float)((U >> 16) & 0xFFu), -kdec, Hs[j + 1024]));
          mv = fmaxf(mv, fmaf((float)(U >> 24),           -kdec, Hs[j + 1536]));
        }
        #pragma unroll
        for (int off = 32; off >= 1; off >>= 1)
          mv = fmaxf(mv, __shfl_xor(mv, off, 64));
        if (do_diag) mv = fmaxf(mv, Hs[i0 + r] + ldfac);  // diag candidate
        mh[r] = mv;
        float sv = 0.0f;
        for (int t = 0; t < 8; ++t) {
          const int j = t * 64 + lane;
          const unsigned int U = mrow[(r << 9) + j];
          sv += __builtin_amdgcn_exp2f(fmaf((float)(U & 0xFFu),         -kdec, Hs[j]        - mv))
              + __builtin_amdgcn_exp2f(fmaf((float)((U >> 8) & 0xFFu),  -kdec, Hs[j + 512]  - mv))
              + __builtin_amdgcn_exp2f(fmaf((float)((U >> 16) & 0xFFu), -kdec, Hs[j + 1024] - mv))
              + __builtin_amdgcn_exp2f(fmaf((float)(U >> 24),           -kdec, Hs[j + 1536] - mv));
        }
        #pragma unroll
        for (int off = 32; off >= 1; off >>= 1)
          sv += __shfl_xor(sv, off, 64);
        if (do_diag)
          sv += __builtin_amdgcn_exp2f(Hs[i0 + r] + ldfac - mv);  // <= 1
        ss[r] = sv;
      }
    }
  } else {
    // ---------------- R10 recompute path (proven) ----------------
    float qx[8], qy[8], qz[8], qw[8];
    #pragma unroll
    for (int r = 0; r < 8; ++r) {
      const float4 t4 = rowp[b * NP + i0 + r];
      qx[r] = bcastf(t4.x); qy[r] = bcastf(t4.y);
      qz[r] = bcastf(t4.z); qw[r] = bcastf(t4.w);
    }
    for (int t = 0; t < 16; ++t) {
      float4 p[2]; float h[2];
      #pragma unroll
      for (int cc = 0; cc < 2; ++cc) {
        const int j = (t * 2 + cc) * 64 + lane;
        p[cc] = Pts[j];
        h[cc] = Hs[j];
      }
      #pragma unroll
      for (int r = 0; r < 8; ++r) {
        #pragma unroll
        for (int cc = 0; cc < 2; ++cc) {
          const float dt = fmaf(qx[r], p[cc].x,
                            fmaf(qy[r], p[cc].y,
                             fmaf(qz[r], p[cc].z, qw[r] * p[cc].w)));
          const float u  = fmaxf(1.0f - fabsf(dt), 1e-6f);
          const float sq = __builtin_amdgcn_sqrtf(u);
          const float pl = fmaf(fmaf(fmaf(B3, u, B2), u, B1), u, B0);
          const float v  = fmaf(sq, -pl, h[cc]);
          ss[r] += __builtin_amdgcn_exp2f(v - mh[r]);
        }
      }
    }
    #pragma unroll
    for (int r = 0; r < 8; ++r) {
      float sv = ss[r];
      #pragma unroll
      for (int off = 32; off >= 1; off >>= 1)
        sv += __shfl_xor(sv, off, 64);
      ss[r] = sv;
    }
    #pragma unroll
    for (int r = 0; r < 8; ++r) {
      const bool good = (ss[r] >= 8.6736174e-19f) && (ss[r] <= 1.1529215e18f);
      if (!good) {
        float mv = -3.0e38f;
        for (int t = 0; t < 32; ++t) {
          const int j = t * 64 + lane;
          const float4 p = Pts[j];
          const float dt = fmaf(qx[r], p.x,
                            fmaf(qy[r], p.y, fmaf(qz[r], p.z, qw[r] * p.w)));
          const float u  = fmaxf(1.0f - fabsf(dt), 1e-6f);
          const float sq = __builtin_amdgcn_sqrtf(u);
          const float pl = fmaf(fmaf(fmaf(B3, u, B2), u, B1), u, B0);
          mv = fmaxf(mv, fmaf(sq, -pl, Hs[j]));
        }
        #pragma unroll
        for (int off = 32; off >= 1; off >>= 1)
          mv = fmaxf(mv, __shfl_xor(mv, off, 64));
        mh[r] = mv;
        float sv = 0.0f;
        for (int t = 0; t < 32; ++t) {
          const int j = t * 64 + lane;
          const float4 p = Pts[j];
          const float dt = fmaf(qx[r], p.x,
                            fmaf(qy[r], p.y, fmaf(qz[r], p.z, qw[r] * p.w)));
          const float u  = fmaxf(1.0f - fabsf(dt), 1e-6f);
          const float sq = __builtin_amdgcn_sqrtf(u);
          const float pl = fmaf(fmaf(fmaf(B3, u, B2), u, B1), u, B0);
          sv += __builtin_amdgcn_exp2f(fmaf(sq, -pl, Hs[j]) - mh[r]);
        }
        #pragma unroll
        for (int off = 32; off >= 1; off >>= 1)
          sv += __shfl_xor(sv, off, 64);
        ss[r] = sv;
      }
    }
  }

  if (lane == 0) {
    #pragma unroll
    for (int r = 0; r < 8; ++r) {
      float res = -eps * 0.69314718055994531f
                * (mh[r] + __builtin_amdgcn_logf(ss[r]));
      if (use_avg) res = 0.5f * (pot_old[oidx + r] + res);
      pot_new[oidx + r] = res;
    }
  }
}

__global__ __launch_bounds__(256) void loss_kernel(
    const float* __restrict__ pot, const float* __restrict__ wx,
    const float* __restrict__ wy, float* __restrict__ out)
{
  const int tid = threadIdx.x;
  double acc = 0.0;
  for (int idx = tid; idx < NPOT; idx += 256) {
    acc += (double)wx[idx] * ((double)pot[0 * NPOT + idx] - (double)pot[2 * NPOT + idx]);
    acc += (double)wy[idx] * ((double)pot[1 * NPOT + idx] - (double)pot[3 * NPOT + idx]);
  }
  #pragma unroll
  for (int off = 32; off >= 1; off >>= 1)
    acc += __shfl_xor(acc, off, 64);
  __shared__ double wsum[4];
  if ((tid & 63) == 0) wsum[tid >> 6] = acc;
  __syncthreads();
  if (tid == 0)
    out[0] = (float)((wsum[0] + wsum[1] + wsum[2] + wsum[3]) / (double)BATCH);
}

extern "C" void kernel_launch(void* const* d_in, const int* in_sizes, int n_in,
                              void* d_out, int out_size, void* d_ws, size_t ws_size,
                              hipStream_t stream)
{
  const float* x  = (const float*)d_in[0];
  const float* y  = (const float*)d_in[1];
  const float* wx = (const float*)d_in[2];
  const float* wy = (const float*)d_in[3];

  const size_t potBytes = (size_t)2 * 4 * NPOT * 4;   // 524,288
  int n_mats = 0;
  if      (ws_size >= 4 * MAT_BYTES + potBytes) n_mats = 4;
  else if (ws_size >= 3 * MAT_BYTES + potBytes) n_mats = 3;
  else if (ws_size >= 2 * MAT_BYTES + potBytes) n_mats = 2;
  else if (ws_size >= 1 * MAT_BYTES + potBytes) n_mats = 1;

  unsigned int* mats = (unsigned int*)d_ws;
  float* pot[2];
  pot[0] = (float*)((char*)d_ws + (size_t)n_mats * MAT_BYTES);
  pot[1] = pot[0] + 4 * NPOT;

  // geomloss epsilon_schedule(p=2, diameter=3.15, blur=0.01, scaling=0.5)
  double eps_list[16]; int ne = 0;
  eps_list[ne++] = 3.15 * 3.15;
  const double stop = 2.0 * log(0.01), step = 2.0 * log(0.5);
  for (double e = 2.0 * log(3.15); e > stop; e += step) eps_list[ne++] = exp(e);
  eps_list[ne++] = 0.01 * 0.01;   // ne == 11

  const double LOG2E = 1.4426950408889634;
  const double PI    = 3.14159265358979323846;
  // acos(d) ~= sqrt(u)*(b0 + b1 u + b2 u^2 + b3 u^3), u = 1-d, |err|<=6.7e-5
  const double b0 = 1.4141461, b1 = 0.1197803, b2 = 0.0180731, b3 = 0.0187293;
  const double cdiag = 2.0 * acos(1.0 - 1e-6);   // exact diag cost 2.8284e-3
  const dim3 grid(1024), blkPass(512), blkLoss(256);
  int cur = 0;

  // ---- fused init pass: computes + stores u8 mats, writes pot[1] ----
  {
    const double e  = eps_list[0];
    const double S2 = 2.0 * 255.0 / PI;
    const double sc = 2.0 * LOG2E / e;
    const double kd = (PI / 255.0) * (LOG2E / e);
    hipLaunchKernelGGL(sink_init_fused, grid, blkPass, 0, stream,
        x, y, wx, wy, mats, n_mats, pot[1 - cur],
        (float)e, (float)kd,
        (float)(b0 * S2), (float)(b1 * S2), (float)(b2 * S2), (float)(b3 * S2),
        (float)(b0 * sc), (float)(b1 * sc), (float)(b2 * sc), (float)(b3 * sc));
    cur ^= 1;
  }

  auto launch_pass = [&](double e, int avg) {
    const double sc = 2.0 * LOG2E / e;
    const double kd = (PI / 255.0) * (LOG2E / e);
    const double efac = exp(-cdiag / e) - exp(-PI / e);
    const double ldf  = log(efac) * LOG2E;
    hipLaunchKernelGGL(sink_pass_r20, grid, blkPass, 0, stream,
        x, y, wx, wy, mats, n_mats, pot[cur], pot[1 - cur],
        (float)e, (float)(LOG2E / e), (float)(-LOG2E / e),
        (float)kd, (float)ldf,
        (float)(b0 * sc), (float)(b1 * sc), (float)(b2 * sc), (float)(b3 * sc), avg);
    cur ^= 1;
  };

  // annealing loop, averaging update
  for (int k = 0; k < ne; ++k)
    launch_pass(eps_list[k], 1);
  // final extrapolation, replace-mode
  launch_pass(eps_list[ne - 1], 0);

  hipLaunchKernelGGL(loss_kernel, dim3(1), blkLoss, 0, stream,
      pot[cur], wx, wy, (float*)d_out);
}

// Round 10
// 484.146 us; speedup vs baseline: 9.3876x; 9.3876x over previous
//
#include <hip/hip_runtime.h>
#include <math.h>

// Sinkhorn divergence (geomloss 'sinkhorn', debias=True) with quaternion
// geodesic cost, B=8, P=2048, D=4.
//
// R21 = R17 verbatim (the proven 488us configuration). R20's uint4-widened
// decode spilled to scratch (launch_bounds(512,8) caps VGPR at 64; the
// widened loop needed ~80) -> 130MB of spill writes per pass, 378us/pass,
// total 4545us. REVERTED to the dword decode.
//
// Final structure and why each piece is at its floor:
//  * init (81us, VALU 82%): fused precompute+init-softmin; 134M quaternion
//    costs via 4-fma dot + sqrt + cubic poly; u8 codes packed and stored
//    (diag byte forced to 255 = cost pi for symmetric mats); softmin from
//    UNROUNDED costs (diag exact via u>=1e-6 clip, no residual).
//  * pass 0 (~130us): first reader of the freshly-written 128MiB mats pays
//    a demand-driven migration toll (~105us). Proven unavoidable: warm
//    reader (R15, +toll stays), NT stores (R17, neutral), 81us time-decay
//    (R18, only ~15% decays), __threadfence_system (R19, 81->305us init).
//    The first decode pass overlaps the toll with useful streaming = optimal.
//  * 11 steady passes (24.6us each): decode u8 + exp2-softmin, streaming
//    134MB/pass at ~5.45 TB/s (~87% of the 6.29 TB/s measured ceiling) with
//    one dword load per lane per step; uint4 widening exceeds the VGPR
//    envelope (R20). Cancellation-free diag residual exp2(h_i-mh+ldfac).
//  * loss (2us).
// Numerics: u8 decode err <= pi/510 per element, zero-mean -> ~1e-4 in the
// loss; diag exact; safety-net two-phase re-sweep for out-of-band rows.
// Tiered n_mats {4..0} by ws_size; missing mats use the R10 recompute path.
// Packing: dword at (row*512 + t*64 + lane) packs cols {j, j+512, j+1024,
// j+1536}, j = t*64+lane -- coalesced global access, conflict-free LDS reads.

#define BATCH 8
#define NP    2048
#define NPOT  (BATCH * NP)                    // 16384 floats per potential
#define MAT_ELEMS  ((size_t)BATCH * NP * NP)  // 33,554,432 u8 per matrix
#define MAT_DWORDS (MAT_ELEMS / 4)            // 8,388,608 dwords
#define MAT_BYTES  (MAT_ELEMS)                // 33,554,432 bytes (32 MiB)

__device__ __forceinline__ float bcastf(float v) {
  return __int_as_float(__builtin_amdgcn_readfirstlane(__float_as_int(v)));
}

// unrounded cost in u8 code units: 2*acos(|<q,p>|) * 255/pi
__device__ __forceinline__ float qcostf(
    float qx, float qy, float qz, float qw, float4 p,
    float P0, float P1, float P2, float P3)
{
  const float dt = fmaf(qx, p.x, fmaf(qy, p.y, fmaf(qz, p.z, qw * p.w)));
  const float u  = fmaxf(1.0f - fabsf(dt), 1e-6f);
  const float sq = __builtin_amdgcn_sqrtf(u);
  const float g  = fmaf(fmaf(fmaf(P3, u, P2), u, P1), u, P0);
  return sq * g;   // in [0, 255.01]
}

// ---------------------------------------------------------------------------
// Fused init pass: computes float costs (code units), packs u8 codes,
// stores them for s < n_mats, computes the init softmin (mh=0, Hs=log2(w))
// from the UNROUNDED costs. Replace-mode output.
// s=0: rows=x cols=y (Cxy); s=1: rows=y cols=x (Cyx);
// s=2: rows=x cols=x (Cxx); s=3: rows=y cols=y (Cyy).
// ---------------------------------------------------------------------------
__global__ __launch_bounds__(512, 8) void sink_init_fused(
    const float* __restrict__ x, const float* __restrict__ y,
    const float* __restrict__ wx, const float* __restrict__ wy,
    unsigned int* __restrict__ mats, int n_mats,
    float* __restrict__ pot_new,
    float eps, float kdec,
    float P0, float P1, float P2, float P3,
    float B0, float B1, float B2, float B3)
{
  const int bid  = blockIdx.x;         // grid 1024: s(4) x b(8) x rg(32)
  const int s    = bid >> 8;
  const int b    = (bid >> 5) & 7;
  const int rg   = bid & 31;
  const int tid  = threadIdx.x;
  const int lane = tid & 63;

  __shared__ float4 Pts[NP];   // 32 KB
  __shared__ float  Hs[NP];    //  8 KB

  const float4* colp; const float* colw; const float4* rowp;
  if (s == 0)      { colp=(const float4*)y; colw=wy; rowp=(const float4*)x; }
  else if (s == 1) { colp=(const float4*)x; colw=wx; rowp=(const float4*)y; }
  else if (s == 2) { colp=(const float4*)x; colw=wx; rowp=(const float4*)x; }
  else             { colp=(const float4*)y; colw=wy; rowp=(const float4*)y; }
  colp += b * NP; colw += b * NP;

  #pragma unroll
  for (int t = 0; t < 4; ++t) {
    const int idx = tid + t * 512;
    Pts[idx] = colp[idx];
    Hs[idx]  = __builtin_amdgcn_logf(colw[idx]);   // log2(w); NO pot read
  }
  __syncthreads();

  const int wvu = __builtin_amdgcn_readfirstlane(tid >> 6);
  const int i0  = rg * 64 + wvu * 8;
  const int oidx = s * NPOT + b * NP + i0;
  const bool dg    = (s >= 2);
  const bool store = (s < n_mats);

  float qx[8], qy[8], qz[8], qw[8];
  #pragma unroll
  for (int r = 0; r < 8; ++r) {
    const float4 t4 = rowp[b * NP + i0 + r];
    qx[r] = bcastf(t4.x); qy[r] = bcastf(t4.y);
    qz[r] = bcastf(t4.z); qw[r] = bcastf(t4.w);
  }

  unsigned int* obase = mats + (size_t)s * MAT_DWORDS
                      + (((size_t)(b * NP + i0)) << 9);

  float mh[8];
  float ss[8];
  #pragma unroll
  for (int r = 0; r < 8; ++r) { mh[r] = 0.0f; ss[r] = 0.0f; }

  for (int t = 0; t < 8; ++t) {
    const int j = t * 64 + lane;
    const float4 p0 = Pts[j];
    const float4 p1 = Pts[j + 512];
    const float4 p2 = Pts[j + 1024];
    const float4 p3 = Pts[j + 1536];
    const float h0 = Hs[j];
    const float h1 = Hs[j + 512];
    const float h2 = Hs[j + 1024];
    const float h3 = Hs[j + 1536];
    #pragma unroll
    for (int r = 0; r < 8; ++r) {
      const float c0 = qcostf(qx[r], qy[r], qz[r], qw[r], p0, P0, P1, P2, P3);
      const float c1 = qcostf(qx[r], qy[r], qz[r], qw[r], p1, P0, P1, P2, P3);
      const float c2 = qcostf(qx[r], qy[r], qz[r], qw[r], p2, P0, P1, P2, P3);
      const float c3 = qcostf(qx[r], qy[r], qz[r], qw[r], p3, P0, P1, P2, P3);
      if (store) {
        const unsigned int a0 = (unsigned int)(c0 + 0.5f);
        const unsigned int a1 = (unsigned int)(c1 + 0.5f);
        const unsigned int a2 = (unsigned int)(c2 + 0.5f);
        const unsigned int a3 = (unsigned int)(c3 + 0.5f);
        unsigned int pack = a0 | (a1 << 8) | (a2 << 16) | (a3 << 24);
        if (dg) {
          const int c = i0 + r;                  // diag column for this row
          if (j == (c & 511))
            pack |= 0xFFu << ((c >> 9) << 3);    // diag code 0 -> OR sets 255
        }
        obase[(r << 9) + j] = pack;
      }
      // softmin from the unrounded costs (diag exact via the u>=1e-6 clip)
      ss[r] += __builtin_amdgcn_exp2f(fmaf(c0, -kdec, h0))
             + __builtin_amdgcn_exp2f(fmaf(c1, -kdec, h1))
             + __builtin_amdgcn_exp2f(fmaf(c2, -kdec, h2))
             + __builtin_amdgcn_exp2f(fmaf(c3, -kdec, h3));
    }
  }
  #pragma unroll
  for (int r = 0; r < 8; ++r) {
    float sv = ss[r];
    #pragma unroll
    for (int off = 32; off >= 1; off >>= 1)
      sv += __shfl_xor(sv, off, 64);
    ss[r] = sv;
  }

  // safety net: full-precision recompute from Pts (independent of mats)
  #pragma unroll
  for (int r = 0; r < 8; ++r) {
    const bool good = (ss[r] >= 8.6736174e-19f) && (ss[r] <= 1.1529215e18f);
    if (!good) {
      float mv = -3.0e38f;
      for (int t = 0; t < 32; ++t) {
        const int j = t * 64 + lane;
        const float4 p = Pts[j];
        const float dt = fmaf(qx[r], p.x,
                          fmaf(qy[r], p.y, fmaf(qz[r], p.z, qw[r] * p.w)));
        const float u  = fmaxf(1.0f - fabsf(dt), 1e-6f);
        const float sq = __builtin_amdgcn_sqrtf(u);
        const float pl = fmaf(fmaf(fmaf(B3, u, B2), u, B1), u, B0);
        mv = fmaxf(mv, fmaf(sq, -pl, Hs[j]));
      }
      #pragma unroll
      for (int off = 32; off >= 1; off >>= 1)
        mv = fmaxf(mv, __shfl_xor(mv, off, 64));
      mh[r] = mv;
      float sv = 0.0f;
      for (int t = 0; t < 32; ++t) {
        const int j = t * 64 + lane;
        const float4 p = Pts[j];
        const float dt = fmaf(qx[r], p.x,
                          fmaf(qy[r], p.y, fmaf(qz[r], p.z, qw[r] * p.w)));
        const float u  = fmaxf(1.0f - fabsf(dt), 1e-6f);
        const float sq = __builtin_amdgcn_sqrtf(u);
        const float pl = fmaf(fmaf(fmaf(B3, u, B2), u, B1), u, B0);
        sv += __builtin_amdgcn_exp2f(fmaf(sq, -pl, Hs[j]) - mv);
      }
      #pragma unroll
      for (int off = 32; off >= 1; off >>= 1)
        sv += __shfl_xor(sv, off, 64);
      ss[r] = sv;
    }
  }

  if (lane == 0) {
    #pragma unroll
    for (int r = 0; r < 8; ++r)
      pot_new[oidx + r] = -eps * 0.69314718055994531f
                        * (mh[r] + __builtin_amdgcn_logf(ss[r]));
  }
}

// ---------------------------------------------------------------------------
// Steady pass: s < n_mats -> u8 decode path (dword loads, R17-proven);
// else R10 recompute path.
// ---------------------------------------------------------------------------
__global__ __launch_bounds__(512, 8) void sink_pass_r21(
    const float* __restrict__ x, const float* __restrict__ y,
    const float* __restrict__ wx, const float* __restrict__ wy,
    const unsigned int* __restrict__ mats, int n_mats,
    const float* __restrict__ pot_old, float* __restrict__ pot_new,
    float eps, float c1 /* log2e/eps */,
    float seed_s /* -log2e/eps */,
    float kdec /* (pi/255)*log2e/eps */,
    float ldfac /* log2(exp(-C_diag/eps) - exp(-pi/eps)) */,
    float B0, float B1, float B2, float B3 /* acos(u)-poly * 2*log2e/eps */,
    int use_avg)
{
  const int bid  = blockIdx.x;         // grid 1024: s(4) x b(8) x rg(32)
  const int s    = bid >> 8;
  const int b    = (bid >> 5) & 7;
  const int rg   = bid & 31;
  const int tid  = threadIdx.x;
  const int lane = tid & 63;

  __shared__ float4 Pts[NP];   // 32 KB (recompute path only)
  __shared__ float  Hs[NP];    //  8 KB

  const float4* colp; const float* colw; const float* colpot; const float4* rowp;
  if (s == 0)      { colp=(const float4*)y; colw=wy; colpot=pot_old+1*NPOT; rowp=(const float4*)x; }
  else if (s == 1) { colp=(const float4*)x; colw=wx; colpot=pot_old+0*NPOT; rowp=(const float4*)y; }
  else if (s == 2) { colp=(const float4*)x; colw=wx; colpot=pot_old+2*NPOT; rowp=(const float4*)x; }
  else             { colp=(const float4*)y; colw=wy; colpot=pot_old+3*NPOT; rowp=(const float4*)y; }
  colp += b * NP; colw += b * NP; colpot += b * NP;

  const bool use_mat = (s < n_mats);
  const bool do_diag = use_mat && (s >= 2);

  if (use_mat) {
    #pragma unroll
    for (int t = 0; t < 4; ++t) {
      const int idx = tid + t * 512;
      Hs[idx] = fmaf(colpot[idx], c1, __builtin_amdgcn_logf(colw[idx]));
    }
  } else {
    #pragma unroll
    for (int t = 0; t < 4; ++t) {
      const int idx = tid + t * 512;
      Pts[idx] = colp[idx];
      Hs[idx] = fmaf(colpot[idx], c1, __builtin_amdgcn_logf(colw[idx]));
    }
  }
  __syncthreads();

  const int wvu = __builtin_amdgcn_readfirstlane(tid >> 6);
  const int i0  = rg * 64 + wvu * 8;
  const int oidx = s * NPOT + b * NP + i0;
  float mh[8];
  #pragma unroll
  for (int r = 0; r < 8; ++r)
    mh[r] = bcastf(pot_old[oidx + r] * seed_s);

  float ss[8] = {0.f, 0.f, 0.f, 0.f, 0.f, 0.f, 0.f, 0.f};

  if (use_mat) {
    // ---------------- u8 decode path ----------------
    const unsigned int* mrow = mats + (size_t)s * MAT_DWORDS
                             + (((size_t)(b * NP + i0)) << 9);
    for (int t = 0; t < 8; ++t) {
      const int j = t * 64 + lane;
      const float h0 = Hs[j];
      const float h1 = Hs[j + 512];
      const float h2 = Hs[j + 1024];
      const float h3 = Hs[j + 1536];
      #pragma unroll
      for (int r = 0; r < 8; ++r) {
        const unsigned int U = mrow[(r << 9) + j];
        const float a0 = (float)(U & 0xFFu);          // v_cvt_f32_ubyte0
        const float a1 = (float)((U >> 8) & 0xFFu);   // v_cvt_f32_ubyte1
        const float a2 = (float)((U >> 16) & 0xFFu);  // v_cvt_f32_ubyte2
        const float a3 = (float)(U >> 24);            // v_cvt_f32_ubyte3
        ss[r] += __builtin_amdgcn_exp2f(fmaf(a0, -kdec, h0 - mh[r]))
               + __builtin_amdgcn_exp2f(fmaf(a1, -kdec, h1 - mh[r]))
               + __builtin_amdgcn_exp2f(fmaf(a2, -kdec, h2 - mh[r]))
               + __builtin_amdgcn_exp2f(fmaf(a3, -kdec, h3 - mh[r]));
      }
    }
    #pragma unroll
    for (int r = 0; r < 8; ++r) {
      float sv = ss[r];
      #pragma unroll
      for (int off = 32; off >= 1; off >>= 1)
        sv += __shfl_xor(sv, off, 64);
      if (do_diag)
        sv += __builtin_amdgcn_exp2f(Hs[i0 + r] - mh[r] + ldfac);
      ss[r] = sv;
    }
    // safety net: two-phase decode re-sweep for out-of-band rows
    #pragma unroll
    for (int r = 0; r < 8; ++r) {
      const bool good = (ss[r] >= 8.6736174e-19f) && (ss[r] <= 1.1529215e18f);
      if (!good) {
        float mv = -3.0e38f;
        for (int t = 0; t < 8; ++t) {
          const int j = t * 64 + lane;
          const unsigned int U = mrow[(r << 9) + j];
          mv = fmaxf(mv, fmaf((float)(U & 0xFFu),         -kdec, Hs[j]));
          mv = fmaxf(mv, fmaf((float)((U >> 8) & 0xFFu),  -kdec, Hs[j + 512]));
          mv = fmaxf(mv, fmaf((float)((U >> 16) & 0xFFu), -kdec, Hs[j + 1024]));
          mv = fmaxf(mv, fmaf((float)(U >> 24),           -kdec, Hs[j + 1536]));
        }
        #pragma unroll
        for (int off = 32; off >= 1; off >>= 1)
          mv = fmaxf(mv, __shfl_xor(mv, off, 64));
        if (do_diag) mv = fmaxf(mv, Hs[i0 + r] + ldfac);  // diag candidate
        mh[r] = mv;
        float sv = 0.0f;
        for (int t = 0; t < 8; ++t) {
          const int j = t * 64 + lane;
          const unsigned int U = mrow[(r << 9) + j];
          sv += __builtin_amdgcn_exp2f(fmaf((float)(U & 0xFFu),         -kdec, Hs[j]        - mv))
              + __builtin_amdgcn_exp2f(fmaf((float)((U >> 8) & 0xFFu),  -kdec, Hs[j + 512]  - mv))
              + __builtin_amdgcn_exp2f(fmaf((float)((U >> 16) & 0xFFu), -kdec, Hs[j + 1024] - mv))
              + __builtin_amdgcn_exp2f(fmaf((float)(U >> 24),           -kdec, Hs[j + 1536] - mv));
        }
        #pragma unroll
        for (int off = 32; off >= 1; off >>= 1)
          sv += __shfl_xor(sv, off, 64);
        if (do_diag)
          sv += __builtin_amdgcn_exp2f(Hs[i0 + r] + ldfac - mv);  // <= 1
        ss[r] = sv;
      }
    }
  } else {
    // ---------------- R10 recompute path (proven) ----------------
    float qx[8], qy[8], qz[8], qw[8];
    #pragma unroll
    for (int r = 0; r < 8; ++r) {
      const float4 t4 = rowp[b * NP + i0 + r];
      qx[r] = bcastf(t4.x); qy[r] = bcastf(t4.y);
      qz[r] = bcastf(t4.z); qw[r] = bcastf(t4.w);
    }
    for (int t = 0; t < 16; ++t) {
      float4 p[2]; float h[2];
      #pragma unroll
      for (int cc = 0; cc < 2; ++cc) {
        const int j = (t * 2 + cc) * 64 + lane;
        p[cc] = Pts[j];
        h[cc] = Hs[j];
      }
      #pragma unroll
      for (int r = 0; r < 8; ++r) {
        #pragma unroll
        for (int cc = 0; cc < 2; ++cc) {
          const float dt = fmaf(qx[r], p[cc].x,
                            fmaf(qy[r], p[cc].y,
                             fmaf(qz[r], p[cc].z, qw[r] * p[cc].w)));
          const float u  = fmaxf(1.0f - fabsf(dt), 1e-6f);
          const float sq = __builtin_amdgcn_sqrtf(u);
          const float pl = fmaf(fmaf(fmaf(B3, u, B2), u, B1), u, B0);
          const float v  = fmaf(sq, -pl, h[cc]);
          ss[r] += __builtin_amdgcn_exp2f(v - mh[r]);
        }
      }
    }
    #pragma unroll
    for (int r = 0; r < 8; ++r) {
      float sv = ss[r];
      #pragma unroll
      for (int off = 32; off >= 1; off >>= 1)
        sv += __shfl_xor(sv, off, 64);
      ss[r] = sv;
    }
    #pragma unroll
    for (int r = 0; r < 8; ++r) {
      const bool good = (ss[r] >= 8.6736174e-19f) && (ss[r] <= 1.1529215e18f);
      if (!good) {
        float mv = -3.0e38f;
        for (int t = 0; t < 32; ++t) {
          const int j = t * 64 + lane;
          const float4 p = Pts[j];
          const float dt = fmaf(qx[r], p.x,
                            fmaf(qy[r], p.y, fmaf(qz[r], p.z, qw[r] * p.w)));
          const float u  = fmaxf(1.0f - fabsf(dt), 1e-6f);
          const float sq = __builtin_amdgcn_sqrtf(u);
          const float pl = fmaf(fmaf(fmaf(B3, u, B2), u, B1), u, B0);
          mv = fmaxf(mv, fmaf(sq, -pl, Hs[j]));
        }
        #pragma unroll
        for (int off = 32; off >= 1; off >>= 1)
          mv = fmaxf(mv, __shfl_xor(mv, off, 64));
        mh[r] = mv;
        float sv = 0.0f;
        for (int t = 0; t < 32; ++t) {
          const int j = t * 64 + lane;
          const float4 p = Pts[j];
          const float dt = fmaf(qx[r], p.x,
                            fmaf(qy[r], p.y, fmaf(qz[r], p.z, qw[r] * p.w)));
          const float u  = fmaxf(1.0f - fabsf(dt), 1e-6f);
          const float sq = __builtin_amdgcn_sqrtf(u);
          const float pl = fmaf(fmaf(fmaf(B3, u, B2), u, B1), u, B0);
          sv += __builtin_amdgcn_exp2f(fmaf(sq, -pl, Hs[j]) - mh[r]);
        }
        #pragma unroll
        for (int off = 32; off >= 1; off >>= 1)
          sv += __shfl_xor(sv, off, 64);
        ss[r] = sv;
      }
    }
  }

  if (lane == 0) {
    #pragma unroll
    for (int r = 0; r < 8; ++r) {
      float res = -eps * 0.69314718055994531f
                * (mh[r] + __builtin_amdgcn_logf(ss[r]));
      if (use_avg) res = 0.5f * (pot_old[oidx + r] + res);
      pot_new[oidx + r] = res;
    }
  }
}

__global__ __launch_bounds__(256) void loss_kernel(
    const float* __restrict__ pot, const float* __restrict__ wx,
    const float* __restrict__ wy, float* __restrict__ out)
{
  const int tid = threadIdx.x;
  double acc = 0.0;
  for (int idx = tid; idx < NPOT; idx += 256) {
    acc += (double)wx[idx] * ((double)pot[0 * NPOT + idx] - (double)pot[2 * NPOT + idx]);
    acc += (double)wy[idx] * ((double)pot[1 * NPOT + idx] - (double)pot[3 * NPOT + idx]);
  }
  #pragma unroll
  for (int off = 32; off >= 1; off >>= 1)
    acc += __shfl_xor(acc, off, 64);
  __shared__ double wsum[4];
  if ((tid & 63) == 0) wsum[tid >> 6] = acc;
  __syncthreads();
  if (tid == 0)
    out[0] = (float)((wsum[0] + wsum[1] + wsum[2] + wsum[3]) / (double)BATCH);
}

extern "C" void kernel_launch(void* const* d_in, const int* in_sizes, int n_in,
                              void* d_out, int out_size, void* d_ws, size_t ws_size,
                              hipStream_t stream)
{
  const float* x  = (const float*)d_in[0];
  const float* y  = (const float*)d_in[1];
  const float* wx = (const float*)d_in[2];
  const float* wy = (const float*)d_in[3];

  const size_t potBytes = (size_t)2 * 4 * NPOT * 4;   // 524,288
  int n_mats = 0;
  if      (ws_size >= 4 * MAT_BYTES + potBytes) n_mats = 4;
  else if (ws_size >= 3 * MAT_BYTES + potBytes) n_mats = 3;
  else if (ws_size >= 2 * MAT_BYTES + potBytes) n_mats = 2;
  else if (ws_size >= 1 * MAT_BYTES + potBytes) n_mats = 1;

  unsigned int* mats = (unsigned int*)d_ws;
  float* pot[2];
  pot[0] = (float*)((char*)d_ws + (size_t)n_mats * MAT_BYTES);
  pot[1] = pot[0] + 4 * NPOT;

  // geomloss epsilon_schedule(p=2, diameter=3.15, blur=0.01, scaling=0.5)
  double eps_list[16]; int ne = 0;
  eps_list[ne++] = 3.15 * 3.15;
  const double stop = 2.0 * log(0.01), step = 2.0 * log(0.5);
  for (double e = 2.0 * log(3.15); e > stop; e += step) eps_list[ne++] = exp(e);
  eps_list[ne++] = 0.01 * 0.01;   // ne == 11

  const double LOG2E = 1.4426950408889634;
  const double PI    = 3.14159265358979323846;
  // acos(d) ~= sqrt(u)*(b0 + b1 u + b2 u^2 + b3 u^3), u = 1-d, |err|<=6.7e-5
  const double b0 = 1.4141461, b1 = 0.1197803, b2 = 0.0180731, b3 = 0.0187293;
  const double cdiag = 2.0 * acos(1.0 - 1e-6);   // exact diag cost 2.8284e-3
  const dim3 grid(1024), blkPass(512), blkLoss(256);
  int cur = 0;

  // ---- fused init pass: computes + stores u8 mats, writes pot[1] ----
  {
    const double e  = eps_list[0];
    const double S2 = 2.0 * 255.0 / PI;
    const double sc = 2.0 * LOG2E / e;
    const double kd = (PI / 255.0) * (LOG2E / e);
    hipLaunchKernelGGL(sink_init_fused, grid, blkPass, 0, stream,
        x, y, wx, wy, mats, n_mats, pot[1 - cur],
        (float)e, (float)kd,
        (float)(b0 * S2), (float)(b1 * S2), (float)(b2 * S2), (float)(b3 * S2),
        (float)(b0 * sc), (float)(b1 * sc), (float)(b2 * sc), (float)(b3 * sc));
    cur ^= 1;
  }

  auto launch_pass = [&](double e, int avg) {
    const double sc = 2.0 * LOG2E / e;
    const double kd = (PI / 255.0) * (LOG2E / e);
    const double efac = exp(-cdiag / e) - exp(-PI / e);
    const double ldf  = log(efac) * LOG2E;
    hipLaunchKernelGGL(sink_pass_r21, grid, blkPass, 0, stream,
        x, y, wx, wy, mats, n_mats, pot[cur], pot[1 - cur],
        (float)e, (float)(LOG2E / e), (float)(-LOG2E / e),
        (float)kd, (float)ldf,
        (float)(b0 * sc), (float)(b1 * sc), (float)(b2 * sc), (float)(b3 * sc), avg);
    cur ^= 1;
  };

  // annealing loop, averaging update
  for (int k = 0; k < ne; ++k)
    launch_pass(eps_list[k], 1);
  // final extrapolation, replace-mode
  launch_pass(eps_list[ne - 1], 0);

  hipLaunchKernelGGL(loss_kernel, dim3(1), blkLoss, 0, stream,
      pot[cur], wx, wy, (float*)d_out);
}